// Round 1
// baseline (591.140 us; speedup 1.0000x reference)
//
#include <hip/hip_runtime.h>
#include <math.h>

// LocalAggregationLoss:
//   v = normalize(codes)                        [1024,128]
//   d1[b] = sum_k exp(dot(bank[idx_bg[b,k]], v[b]) / T)
//   d2[b] = sum_k exp(dot(bank[idx_cl[b,k]], v[b]) / T)
//   out[b] = log(d1[b]) - log(d2[b])
// Memory-bound random gather: ~210 MB of 512B rows from a 512MB bank.

constexpr int DIM   = 128;
constexpr int KN    = 200;
constexpr float INV_T = 1.0f / 0.07f;

__global__ __launch_bounds__(256, 4)
void lal_kernel(const float* __restrict__ codes,
                const float* __restrict__ bank,
                const int*   __restrict__ idx_bg,
                const int*   __restrict__ idx_cl,
                float*       __restrict__ out)
{
    const int b   = blockIdx.x;
    const int tid = threadIdx.x;

    __shared__ float v[DIM];
    __shared__ float wsum[4];
    __shared__ float red1[8];
    __shared__ float red2[8];
    __shared__ float s_rnorm;

    // ---- normalize codes[b] into LDS ----
    float c  = (tid < DIM) ? codes[b * DIM + tid] : 0.0f;
    float ss = c * c;
    #pragma unroll
    for (int m = 32; m > 0; m >>= 1) ss += __shfl_xor(ss, m, 64);
    if ((tid & 63) == 0) wsum[tid >> 6] = ss;
    __syncthreads();
    if (tid == 0) {
        float t = wsum[0] + wsum[1] + wsum[2] + wsum[3];
        s_rnorm = 1.0f / sqrtf(t);
    }
    __syncthreads();
    if (tid < DIM) v[tid] = c * s_rnorm;
    __syncthreads();

    // ---- gather + dot + exp-sum ----
    // 8 groups of 32 lanes; each group handles one row per array per iter.
    const int group = tid >> 5;   // 0..7
    const int lane  = tid & 31;   // 0..31

    const float4 vv = ((const float4*)v)[lane];   // dims [lane*4 .. lane*4+3]

    const int* ib = idx_bg + b * KN;
    const int* ic = idx_cl + b * KN;

    float sum1 = 0.0f, sum2 = 0.0f;
    for (int k = group; k < KN; k += 8) {
        const int r1 = ib[k];
        const int r2 = ic[k];
        // two independent 512B coalesced row reads in flight per group
        const float4 x1 = ((const float4*)(bank + (size_t)r1 * DIM))[lane];
        const float4 x2 = ((const float4*)(bank + (size_t)r2 * DIM))[lane];
        float d1 = x1.x * vv.x + x1.y * vv.y + x1.z * vv.z + x1.w * vv.w;
        float d2 = x2.x * vv.x + x2.y * vv.y + x2.z * vv.z + x2.w * vv.w;
        // reduce across the 32-lane group (xor masks stay within the half-wave)
        #pragma unroll
        for (int m = 16; m > 0; m >>= 1) {
            d1 += __shfl_xor(d1, m, 64);
            d2 += __shfl_xor(d2, m, 64);
        }
        sum1 += expf(d1 * INV_T);
        sum2 += expf(d2 * INV_T);
    }

    if (lane == 0) { red1[group] = sum1; red2[group] = sum2; }
    __syncthreads();
    if (tid == 0) {
        float D1 = 0.0f, D2 = 0.0f;
        #pragma unroll
        for (int g = 0; g < 8; ++g) { D1 += red1[g]; D2 += red2[g]; }
        out[b] = logf(D1) - logf(D2);
    }
}

extern "C" void kernel_launch(void* const* d_in, const int* in_sizes, int n_in,
                              void* d_out, int out_size, void* d_ws, size_t ws_size,
                              hipStream_t stream)
{
    const float* codes  = (const float*)d_in[0];
    const float* bank   = (const float*)d_in[1];
    const int*   idx_bg = (const int*)d_in[2];
    const int*   idx_cl = (const int*)d_in[3];
    float*       out    = (float*)d_out;

    const int batch = in_sizes[0] / DIM;   // 1024
    lal_kernel<<<batch, 256, 0, stream>>>(codes, bank, idx_bg, idx_cl, out);
}

// Round 2
// 588.233 us; speedup vs baseline: 1.0049x; 1.0049x over previous
//
#include <hip/hip_runtime.h>
#include <math.h>

// LocalAggregationLoss:
//   v = normalize(codes)                        [1024,128]
//   d1[b] = sum_k exp(dot(bank[idx_bg[b,k]], v[b]) / T)
//   d2[b] = sum_k exp(dot(bank[idx_cl[b,k]], v[b]) / T)
//   out[b] = log(d1[b]) - log(d2[b])
// Memory-bound random gather: ~210 MB of 512B rows from a 512MB bank.
// R1: latency-bound fix — LDS-preload indices, unroll x5 so each wave has
// 10 independent 512B row loads in flight before the reduce chains.

constexpr int DIM = 128;
constexpr int KN  = 200;
constexpr int RPG = 25;              // rows per 32-lane group (KN / 8)
constexpr int UF  = 5;               // unroll factor (25 = 5*5)
constexpr float INV_T = 1.0f / 0.07f;

__global__ __launch_bounds__(256, 4)
void lal_kernel(const float* __restrict__ codes,
                const float* __restrict__ bank,
                const int*   __restrict__ idx_bg,
                const int*   __restrict__ idx_cl,
                float*       __restrict__ out)
{
    const int b   = blockIdx.x;
    const int tid = threadIdx.x;

    __shared__ float v[DIM];
    __shared__ int   s_ib[KN];
    __shared__ int   s_ic[KN];
    __shared__ float wsum[4];
    __shared__ float red1[8];
    __shared__ float red2[8];
    __shared__ float s_rnorm;

    // ---- preload all indices into LDS (off the critical path) ----
    if (tid < KN) {
        s_ib[tid] = idx_bg[b * KN + tid];
        s_ic[tid] = idx_cl[b * KN + tid];
    }

    // ---- normalize codes[b] into LDS ----
    float c  = (tid < DIM) ? codes[b * DIM + tid] : 0.0f;
    float ss = c * c;
    #pragma unroll
    for (int m = 32; m > 0; m >>= 1) ss += __shfl_xor(ss, m, 64);
    if ((tid & 63) == 0) wsum[tid >> 6] = ss;
    __syncthreads();
    if (tid == 0) {
        float t = wsum[0] + wsum[1] + wsum[2] + wsum[3];
        s_rnorm = 1.0f / sqrtf(t);
    }
    __syncthreads();
    if (tid < DIM) v[tid] = c * s_rnorm;
    __syncthreads();

    // ---- gather + dot + exp-sum ----
    // 8 groups of 32 lanes; group g owns contiguous rows [g*25, g*25+25).
    const int group = tid >> 5;   // 0..7
    const int lane  = tid & 31;   // 0..31

    const float4 vv = ((const float4*)v)[lane];   // dims [lane*4 .. lane*4+3]
    const int kbase = group * RPG;

    float sum1 = 0.0f, sum2 = 0.0f;

    #pragma unroll 1
    for (int j = 0; j < RPG; j += UF) {
        float4 x1[UF], x2[UF];
        // phase 1: issue 10 independent 512B coalesced row loads
        #pragma unroll
        for (int u = 0; u < UF; ++u) {
            const int r1 = s_ib[kbase + j + u];
            const int r2 = s_ic[kbase + j + u];
            x1[u] = ((const float4*)(bank + (size_t)r1 * DIM))[lane];
            x2[u] = ((const float4*)(bank + (size_t)r2 * DIM))[lane];
        }
        // phase 2: dot + group-reduce + exp (waits are staggered vmcnt(N))
        #pragma unroll
        for (int u = 0; u < UF; ++u) {
            float d1 = x1[u].x * vv.x + x1[u].y * vv.y + x1[u].z * vv.z + x1[u].w * vv.w;
            float d2 = x2[u].x * vv.x + x2[u].y * vv.y + x2[u].z * vv.z + x2[u].w * vv.w;
            #pragma unroll
            for (int m = 16; m > 0; m >>= 1) {
                d1 += __shfl_xor(d1, m, 64);
                d2 += __shfl_xor(d2, m, 64);
            }
            sum1 += __expf(d1 * INV_T);
            sum2 += __expf(d2 * INV_T);
        }
    }

    if (lane == 0) { red1[group] = sum1; red2[group] = sum2; }
    __syncthreads();
    if (tid == 0) {
        float D1 = 0.0f, D2 = 0.0f;
        #pragma unroll
        for (int g = 0; g < 8; ++g) { D1 += red1[g]; D2 += red2[g]; }
        out[b] = logf(D1) - logf(D2);
    }
}

extern "C" void kernel_launch(void* const* d_in, const int* in_sizes, int n_in,
                              void* d_out, int out_size, void* d_ws, size_t ws_size,
                              hipStream_t stream)
{
    const float* codes  = (const float*)d_in[0];
    const float* bank   = (const float*)d_in[1];
    const int*   idx_bg = (const int*)d_in[2];
    const int*   idx_cl = (const int*)d_in[3];
    float*       out    = (float*)d_out;

    const int batch = in_sizes[0] / DIM;   // 1024
    lal_kernel<<<batch, 256, 0, stream>>>(codes, bank, idx_bg, idx_cl, out);
}